// Round 1
// baseline (505.209 us; speedup 1.0000x reference)
//
#include <hip/hip_runtime.h>

// InfoNCE fused pipeline:
//   gemm1: Z[16384,512] = bf16(h) @ bf16(W)^T  (+ row norm² via atomics)
//   rnorm: r[i] = rsqrt(norm2[i])
//   gemm2: S = Zb[:8192] @ Zb[8192:]^T fused with sim-scale, exp-rowsum,
//          diag and total-sum reductions (S never materialized)
//   finalize: loss = mean(log(rowsumexp)) - mean(diag); sim_pos; sim_mean

typedef __attribute__((ext_vector_type(8))) short bf16x8;   // 8 bf16 = 4 VGPRs
typedef __attribute__((ext_vector_type(4))) float floatx4;  // MFMA C/D frag

__device__ __forceinline__ unsigned short f2bf(float f) {
    union { float f; unsigned u; } v; v.f = f;
    unsigned r = (v.u + 0x7FFFu + ((v.u >> 16) & 1u)) >> 16;   // RNE
    return (unsigned short)r;
}

// ---------------------------------------------------------------- GEMM1
// C[16384,512] = A[16384,2048] @ B[512,2048]^T, fp32 in, bf16 out, + norm²
__global__ __launch_bounds__(256) void gemm1_kernel(
    const float* __restrict__ h, const float* __restrict__ W,
    unsigned short* __restrict__ Zb, float* __restrict__ norm2)
{
    __shared__ __align__(16) unsigned short As[128][40];  // +8 pad: 16B-aligned rows, conflict break
    __shared__ __align__(16) unsigned short Bs[128][40];

    const int bn = blockIdx.x;        // 0..3   (N=512)
    const int bm = blockIdx.y;        // 0..127 (M=16384)
    const int t = threadIdx.x;
    const int wave = t >> 6, lane = t & 63;
    const int wm = wave & 1, wn = wave >> 1;       // 64x64 quadrant per wave
    const int quad = lane >> 4, l15 = lane & 15;

    floatx4 acc[4][4];
    #pragma unroll
    for (int i = 0; i < 4; i++)
        #pragma unroll
        for (int j = 0; j < 4; j++) acc[i][j] = {0.f, 0.f, 0.f, 0.f};

    const int lrow = t >> 1;          // 0..127 staging row
    const int lhalf = t & 1;          // which 16-float half of BK=32
    const float* ga = h + (size_t)(bm * 128 + lrow) * 2048 + lhalf * 16;
    const float* gb = W + (size_t)(bn * 128 + lrow) * 2048 + lhalf * 16;

    for (int k0 = 0; k0 < 2048; k0 += 32) {
        #pragma unroll
        for (int c = 0; c < 4; c++) {
            const float4 va = *reinterpret_cast<const float4*>(ga + k0 + c * 4);
            const float4 vb = *reinterpret_cast<const float4*>(gb + k0 + c * 4);
            ushort4 ua = make_ushort4(f2bf(va.x), f2bf(va.y), f2bf(va.z), f2bf(va.w));
            ushort4 ub = make_ushort4(f2bf(vb.x), f2bf(vb.y), f2bf(vb.z), f2bf(vb.w));
            *reinterpret_cast<ushort4*>(&As[lrow][lhalf * 16 + c * 4]) = ua;
            *reinterpret_cast<ushort4*>(&Bs[lrow][lhalf * 16 + c * 4]) = ub;
        }
        __syncthreads();
        bf16x8 af[4], bfr[4];
        #pragma unroll
        for (int i = 0; i < 4; i++)
            af[i] = *reinterpret_cast<const bf16x8*>(&As[wm * 64 + i * 16 + l15][quad * 8]);
        #pragma unroll
        for (int j = 0; j < 4; j++)
            bfr[j] = *reinterpret_cast<const bf16x8*>(&Bs[wn * 64 + j * 16 + l15][quad * 8]);
        #pragma unroll
        for (int i = 0; i < 4; i++)
            #pragma unroll
            for (int j = 0; j < 4; j++)
                acc[i][j] = __builtin_amdgcn_mfma_f32_16x16x32_bf16(af[i], bfr[j], acc[i][j], 0, 0, 0);
        __syncthreads();
    }

    // Epilogue: store bf16 Z, accumulate row norm² (C/D map: col=l15, row=quad*4+r)
    #pragma unroll
    for (int i = 0; i < 4; i++) {
        #pragma unroll
        for (int r = 0; r < 4; r++) {
            const int row_g = bm * 128 + wm * 64 + i * 16 + quad * 4 + r;
            float p = 0.f;
            #pragma unroll
            for (int j = 0; j < 4; j++) {
                const float v = acc[i][j][r];
                const int col_g = bn * 128 + wn * 64 + j * 16 + l15;
                Zb[(size_t)row_g * 512 + col_g] = f2bf(v);
                p += v * v;
            }
            p += __shfl_xor(p, 1, 16);
            p += __shfl_xor(p, 2, 16);
            p += __shfl_xor(p, 4, 16);
            p += __shfl_xor(p, 8, 16);
            if (l15 == 0) atomicAdd(&norm2[row_g], p);
        }
    }
}

// ---------------------------------------------------------------- rnorm
__global__ __launch_bounds__(256) void rnorm_kernel(
    const float* __restrict__ norm2, float* __restrict__ rnorm)
{
    const int i = blockIdx.x * 256 + threadIdx.x;
    if (i < 16384) rnorm[i] = rsqrtf(fmaxf(norm2[i], 1e-30f));
}

// ---------------------------------------------------------------- GEMM2
// S[8192,8192] = Zb[:8192] @ Zb[8192:]^T with fused InfoNCE epilogue
__global__ __launch_bounds__(256) void gemm2_kernel(
    const unsigned short* __restrict__ Zb, const float* __restrict__ rnorm,
    float* __restrict__ rowse, float* __restrict__ bsum, float* __restrict__ bdiag)
{
    __shared__ __align__(16) unsigned short As[128][40];
    __shared__ __align__(16) unsigned short Bs[128][40];
    __shared__ float red[8];

    const int bn = blockIdx.x;        // 0..63
    const int bm = blockIdx.y;        // 0..63
    const int t = threadIdx.x;
    const int wave = t >> 6, lane = t & 63;
    const int wm = wave & 1, wn = wave >> 1;
    const int quad = lane >> 4, l15 = lane & 15;

    const unsigned short* Az = Zb;                       // anchor rows
    const unsigned short* Bz = Zb + (size_t)8192 * 512;  // context rows

    floatx4 acc[4][4];
    #pragma unroll
    for (int i = 0; i < 4; i++)
        #pragma unroll
        for (int j = 0; j < 4; j++) acc[i][j] = {0.f, 0.f, 0.f, 0.f};

    const int lrow = t >> 1, lhalf = t & 1;
    const unsigned short* ga = Az + (size_t)(bm * 128 + lrow) * 512 + lhalf * 16;
    const unsigned short* gb = Bz + (size_t)(bn * 128 + lrow) * 512 + lhalf * 16;

    for (int k0 = 0; k0 < 512; k0 += 32) {
        #pragma unroll
        for (int c = 0; c < 2; c++) {
            const bf16x8 va = *reinterpret_cast<const bf16x8*>(ga + k0 + c * 8);
            const bf16x8 vb = *reinterpret_cast<const bf16x8*>(gb + k0 + c * 8);
            *reinterpret_cast<bf16x8*>(&As[lrow][lhalf * 16 + c * 8]) = va;
            *reinterpret_cast<bf16x8*>(&Bs[lrow][lhalf * 16 + c * 8]) = vb;
        }
        __syncthreads();
        bf16x8 af[4], bfr[4];
        #pragma unroll
        for (int i = 0; i < 4; i++)
            af[i] = *reinterpret_cast<const bf16x8*>(&As[wm * 64 + i * 16 + l15][quad * 8]);
        #pragma unroll
        for (int j = 0; j < 4; j++)
            bfr[j] = *reinterpret_cast<const bf16x8*>(&Bs[wn * 64 + j * 16 + l15][quad * 8]);
        #pragma unroll
        for (int i = 0; i < 4; i++)
            #pragma unroll
            for (int j = 0; j < 4; j++)
                acc[i][j] = __builtin_amdgcn_mfma_f32_16x16x32_bf16(af[i], bfr[j], acc[i][j], 0, 0, 0);
        __syncthreads();
    }

    // Fused epilogue: sim = dot * r_i * r_j / TEMP; rowsumexp, diag, total
    float rc4[4];
    #pragma unroll
    for (int j = 0; j < 4; j++)
        rc4[j] = rnorm[8192 + bn * 128 + wn * 64 + j * 16 + l15];

    float s_total = 0.f, s_diag = 0.f;
    #pragma unroll
    for (int i = 0; i < 4; i++) {
        #pragma unroll
        for (int r = 0; r < 4; r++) {
            const int row_g = bm * 128 + wm * 64 + i * 16 + quad * 4 + r;
            const float rz = rnorm[row_g];
            float rowexp = 0.f;
            #pragma unroll
            for (int j = 0; j < 4; j++) {
                const int col_g = bn * 128 + wn * 64 + j * 16 + l15;
                const float sim = acc[i][j][r] * rz * rc4[j] * 10.0f;  // 1/TEMP
                s_total += sim;
                rowexp += __expf(sim);
                if (col_g == row_g) s_diag += sim;
            }
            rowexp += __shfl_xor(rowexp, 1, 16);
            rowexp += __shfl_xor(rowexp, 2, 16);
            rowexp += __shfl_xor(rowexp, 4, 16);
            rowexp += __shfl_xor(rowexp, 8, 16);
            if (l15 == 0) atomicAdd(&rowse[row_g], rowexp);
        }
    }
    #pragma unroll
    for (int off = 32; off; off >>= 1) {
        s_total += __shfl_xor(s_total, off, 64);
        s_diag  += __shfl_xor(s_diag, off, 64);
    }
    if (lane == 0) { red[wave] = s_total; red[4 + wave] = s_diag; }
    __syncthreads();
    if (t == 0) {
        bsum[bm * 64 + bn]  = red[0] + red[1] + red[2] + red[3];
        bdiag[bm * 64 + bn] = red[4] + red[5] + red[6] + red[7];
    }
}

// ---------------------------------------------------------------- finalize
__global__ __launch_bounds__(256) void finalize_kernel(
    const float* __restrict__ rowse, const float* __restrict__ bsum,
    const float* __restrict__ bdiag, float* __restrict__ out)
{
    float a = 0.f, b = 0.f, c = 0.f;
    for (int i = threadIdx.x; i < 8192; i += 256) a += logf(rowse[i]);
    for (int i = threadIdx.x; i < 4096; i += 256) { b += bsum[i]; c += bdiag[i]; }
    #pragma unroll
    for (int off = 32; off; off >>= 1) {
        a += __shfl_xor(a, off, 64);
        b += __shfl_xor(b, off, 64);
        c += __shfl_xor(c, off, 64);
    }
    __shared__ float ra[4], rb[4], rc[4];
    const int wave = threadIdx.x >> 6, lane = threadIdx.x & 63;
    if (lane == 0) { ra[wave] = a; rb[wave] = b; rc[wave] = c; }
    __syncthreads();
    if (threadIdx.x == 0) {
        const float A = ra[0] + ra[1] + ra[2] + ra[3];
        const float B = rb[0] + rb[1] + rb[2] + rb[3];
        const float C = rc[0] + rc[1] + rc[2] + rc[3];
        const float diag_mean = C / 8192.f;
        out[0] = A / 8192.f - diag_mean;            // loss
        out[1] = diag_mean;                         // sim_pos
        out[2] = B / (8192.f * 8192.f);             // sim_mean
    }
}

// ---------------------------------------------------------------- launch
extern "C" void kernel_launch(void* const* d_in, const int* in_sizes, int n_in,
                              void* d_out, int out_size, void* d_ws, size_t ws_size,
                              hipStream_t stream) {
    const float* h = (const float*)d_in[0];   // [16384, 2048]
    const float* W = (const float*)d_in[1];   // [512, 2048]
    float* out = (float*)d_out;               // [3]

    char* ws = (char*)d_ws;
    float* norm2 = (float*)(ws);              // 16384 f
    float* rowse = (float*)(ws + 65536);      // 8192 f
    float* bsum  = (float*)(ws + 98304);      // 4096 f
    float* bdiag = (float*)(ws + 114688);     // 4096 f
    float* rnorm = (float*)(ws + 131072);     // 16384 f
    unsigned short* Zb = (unsigned short*)(ws + 196608);  // 16384x512 bf16

    hipMemsetAsync(ws, 0, 131072, stream);    // zero all accumulators (ws is poisoned)

    hipLaunchKernelGGL(gemm1_kernel, dim3(4, 128), dim3(256), 0, stream, h, W, Zb, norm2);
    hipLaunchKernelGGL(rnorm_kernel, dim3(64), dim3(256), 0, stream, norm2, rnorm);
    hipLaunchKernelGGL(gemm2_kernel, dim3(64, 64), dim3(256), 0, stream, Zb, rnorm, rowse, bsum, bdiag);
    hipLaunchKernelGGL(finalize_kernel, dim3(1), dim3(256), 0, stream, rowse, bsum, bdiag, out);
}

// Round 2
// 408.934 us; speedup vs baseline: 1.2354x; 1.2354x over previous
//
#include <hip/hip_runtime.h>

// InfoNCE fused pipeline (round 2):
//   cast : h,W fp32 -> bf16 (memory-bound, removes all f2bf from GEMM hot loops)
//   gemm1: Z[16384,512] = hb @ Wb^T (m97-style global_load_lds staging) + row norm^2
//   rnorm: r[i] = rsqrt(norm2[i])
//   gemm2: S = Zb[:8192] @ Zb[8192:]^T fused with sim-scale, exp-rowsum, diag, total
//   finalize: loss = mean(log(rowsumexp)) - mean(diag); sim_pos; sim_mean

typedef __attribute__((ext_vector_type(8))) short bf16x8;   // 8 bf16 = 4 VGPRs
typedef __attribute__((ext_vector_type(8))) short short8;
typedef __attribute__((ext_vector_type(4))) float floatx4;  // MFMA C/D frag

__device__ __forceinline__ unsigned short f2bf(float f) {
    union { float f; unsigned u; } v; v.f = f;
    unsigned r = (v.u + 0x7FFFu + ((v.u >> 16) & 1u)) >> 16;   // RNE
    return (unsigned short)r;
}

// async global->LDS, 16B per lane. LDS dest = wave-uniform base + lane*16.
__device__ __forceinline__ void async_copy16(const void* g, void* l) {
    __builtin_amdgcn_global_load_lds(
        (const __attribute__((address_space(1))) void*)g,
        (__attribute__((address_space(3))) void*)l,
        16, 0, 0);
}

// ---------------------------------------------------------------- cast fp32->bf16
__global__ __launch_bounds__(256) void cast_kernel(
    const float* __restrict__ src, unsigned short* __restrict__ dst, int n)
{
    const int i = (blockIdx.x * 256 + threadIdx.x) * 8;
    if (i + 7 < n) {
        const float4 a = *reinterpret_cast<const float4*>(src + i);
        const float4 b = *reinterpret_cast<const float4*>(src + i + 4);
        short8 o;
        o[0] = (short)f2bf(a.x); o[1] = (short)f2bf(a.y);
        o[2] = (short)f2bf(a.z); o[3] = (short)f2bf(a.w);
        o[4] = (short)f2bf(b.x); o[5] = (short)f2bf(b.y);
        o[6] = (short)f2bf(b.z); o[7] = (short)f2bf(b.w);
        *reinterpret_cast<short8*>(dst + i) = o;
    }
}

// ---------------------------------------------------------------- GEMM1 (fast, bf16 in)
// C[16384,512] = hb[16384,2048] @ Wb[512,2048]^T, + row norm^2, bf16 Z out
__global__ __launch_bounds__(256) void gemm1_fast_kernel(
    const unsigned short* __restrict__ hb, const unsigned short* __restrict__ Wb,
    unsigned short* __restrict__ Zb, float* __restrict__ norm2)
{
    __shared__ __align__(16) unsigned short As[128 * 32];  // unpadded: global_load_lds layout
    __shared__ __align__(16) unsigned short Bs[128 * 32];

    const int bn = blockIdx.x;        // 0..3   (N=512)
    const int bm = blockIdx.y;        // 0..127 (M=16384)
    const int t = threadIdx.x;
    const int wave = t >> 6, lane = t & 63;
    const int wm = wave & 1, wn = wave >> 1;
    const int quad = lane >> 4, l15 = lane & 15;

    floatx4 acc[4][4];
    #pragma unroll
    for (int i = 0; i < 4; i++)
        #pragma unroll
        for (int j = 0; j < 4; j++) acc[i][j] = {0.f, 0.f, 0.f, 0.f};

    // staging: lane -> (row = l>>2, kcol = (l&3)*8); wave w covers rows [w*32, w*32+32)
    const int srow = lane >> 2, skcol = (lane & 3) * 8;
    unsigned short* lA0 = &As[(wave * 32 +  0) * 32];
    unsigned short* lA1 = &As[(wave * 32 + 16) * 32];
    unsigned short* lB0 = &Bs[(wave * 32 +  0) * 32];
    unsigned short* lB1 = &Bs[(wave * 32 + 16) * 32];
    const unsigned short* gA0 = hb + (size_t)(bm * 128 + wave * 32 + srow) * 2048 + skcol;
    const unsigned short* gA1 = gA0 + (size_t)16 * 2048;
    const unsigned short* gB0 = Wb + (size_t)(bn * 128 + wave * 32 + srow) * 2048 + skcol;
    const unsigned short* gB1 = gB0 + (size_t)16 * 2048;

    for (int k0 = 0; k0 < 2048; k0 += 32) {
        async_copy16(gA0 + k0, lA0);
        async_copy16(gA1 + k0, lA1);
        async_copy16(gB0 + k0, lB0);
        async_copy16(gB1 + k0, lB1);
        __syncthreads();
        bf16x8 af[4], bfr[4];
        #pragma unroll
        for (int i = 0; i < 4; i++)
            af[i] = *reinterpret_cast<const bf16x8*>(&As[(wm * 64 + i * 16 + l15) * 32 + quad * 8]);
        #pragma unroll
        for (int j = 0; j < 4; j++)
            bfr[j] = *reinterpret_cast<const bf16x8*>(&Bs[(wn * 64 + j * 16 + l15) * 32 + quad * 8]);
        #pragma unroll
        for (int i = 0; i < 4; i++)
            #pragma unroll
            for (int j = 0; j < 4; j++)
                acc[i][j] = __builtin_amdgcn_mfma_f32_16x16x32_bf16(af[i], bfr[j], acc[i][j], 0, 0, 0);
        __syncthreads();
    }

    // Epilogue: store bf16 Z, accumulate row norm^2 (C/D map: col=l15, row=quad*4+r)
    #pragma unroll
    for (int i = 0; i < 4; i++) {
        #pragma unroll
        for (int r = 0; r < 4; r++) {
            const int row_g = bm * 128 + wm * 64 + i * 16 + quad * 4 + r;
            float p = 0.f;
            #pragma unroll
            for (int j = 0; j < 4; j++) {
                const float v = acc[i][j][r];
                const int col_g = bn * 128 + wn * 64 + j * 16 + l15;
                Zb[(size_t)row_g * 512 + col_g] = f2bf(v);
                p += v * v;
            }
            p += __shfl_xor(p, 1, 16);
            p += __shfl_xor(p, 2, 16);
            p += __shfl_xor(p, 4, 16);
            p += __shfl_xor(p, 8, 16);
            if (l15 == 0) atomicAdd(&norm2[row_g], p);
        }
    }
}

// ---------------------------------------------------------------- GEMM1 (fallback, fp32 in)
__global__ __launch_bounds__(256) void gemm1_slow_kernel(
    const float* __restrict__ h, const float* __restrict__ W,
    unsigned short* __restrict__ Zb, float* __restrict__ norm2)
{
    __shared__ __align__(16) unsigned short As[128][40];
    __shared__ __align__(16) unsigned short Bs[128][40];

    const int bn = blockIdx.x, bm = blockIdx.y;
    const int t = threadIdx.x;
    const int wave = t >> 6, lane = t & 63;
    const int wm = wave & 1, wn = wave >> 1;
    const int quad = lane >> 4, l15 = lane & 15;

    floatx4 acc[4][4];
    #pragma unroll
    for (int i = 0; i < 4; i++)
        #pragma unroll
        for (int j = 0; j < 4; j++) acc[i][j] = {0.f, 0.f, 0.f, 0.f};

    const int lrow = t >> 1, lhalf = t & 1;
    const float* ga = h + (size_t)(bm * 128 + lrow) * 2048 + lhalf * 16;
    const float* gb = W + (size_t)(bn * 128 + lrow) * 2048 + lhalf * 16;

    for (int k0 = 0; k0 < 2048; k0 += 32) {
        #pragma unroll
        for (int c = 0; c < 4; c++) {
            const float4 va = *reinterpret_cast<const float4*>(ga + k0 + c * 4);
            const float4 vb = *reinterpret_cast<const float4*>(gb + k0 + c * 4);
            ushort4 ua = make_ushort4(f2bf(va.x), f2bf(va.y), f2bf(va.z), f2bf(va.w));
            ushort4 ub = make_ushort4(f2bf(vb.x), f2bf(vb.y), f2bf(vb.z), f2bf(vb.w));
            *reinterpret_cast<ushort4*>(&As[lrow][lhalf * 16 + c * 4]) = ua;
            *reinterpret_cast<ushort4*>(&Bs[lrow][lhalf * 16 + c * 4]) = ub;
        }
        __syncthreads();
        bf16x8 af[4], bfr[4];
        #pragma unroll
        for (int i = 0; i < 4; i++)
            af[i] = *reinterpret_cast<const bf16x8*>(&As[wm * 64 + i * 16 + l15][quad * 8]);
        #pragma unroll
        for (int j = 0; j < 4; j++)
            bfr[j] = *reinterpret_cast<const bf16x8*>(&Bs[wn * 64 + j * 16 + l15][quad * 8]);
        #pragma unroll
        for (int i = 0; i < 4; i++)
            #pragma unroll
            for (int j = 0; j < 4; j++)
                acc[i][j] = __builtin_amdgcn_mfma_f32_16x16x32_bf16(af[i], bfr[j], acc[i][j], 0, 0, 0);
        __syncthreads();
    }

    #pragma unroll
    for (int i = 0; i < 4; i++) {
        #pragma unroll
        for (int r = 0; r < 4; r++) {
            const int row_g = bm * 128 + wm * 64 + i * 16 + quad * 4 + r;
            float p = 0.f;
            #pragma unroll
            for (int j = 0; j < 4; j++) {
                const float v = acc[i][j][r];
                const int col_g = bn * 128 + wn * 64 + j * 16 + l15;
                Zb[(size_t)row_g * 512 + col_g] = f2bf(v);
                p += v * v;
            }
            p += __shfl_xor(p, 1, 16);
            p += __shfl_xor(p, 2, 16);
            p += __shfl_xor(p, 4, 16);
            p += __shfl_xor(p, 8, 16);
            if (l15 == 0) atomicAdd(&norm2[row_g], p);
        }
    }
}

// ---------------------------------------------------------------- rnorm
__global__ __launch_bounds__(256) void rnorm_kernel(
    const float* __restrict__ norm2, float* __restrict__ rnorm)
{
    const int i = blockIdx.x * 256 + threadIdx.x;
    if (i < 16384) rnorm[i] = rsqrtf(fmaxf(norm2[i], 1e-30f));
}

// ---------------------------------------------------------------- GEMM2
// S[8192,8192] = Zb[:8192] @ Zb[8192:]^T with fused InfoNCE epilogue (m97 staging)
__global__ __launch_bounds__(256) void gemm2_kernel(
    const unsigned short* __restrict__ Zb, const float* __restrict__ rnorm,
    float* __restrict__ rowse, float* __restrict__ bsum, float* __restrict__ bdiag)
{
    __shared__ __align__(16) unsigned short As[128 * 32];
    __shared__ __align__(16) unsigned short Bs[128 * 32];
    __shared__ float red[8];

    const int bn = blockIdx.x;        // 0..63
    const int bm = blockIdx.y;        // 0..63
    const int t = threadIdx.x;
    const int wave = t >> 6, lane = t & 63;
    const int wm = wave & 1, wn = wave >> 1;
    const int quad = lane >> 4, l15 = lane & 15;

    const unsigned short* Az = Zb;
    const unsigned short* Bz = Zb + (size_t)8192 * 512;

    floatx4 acc[4][4];
    #pragma unroll
    for (int i = 0; i < 4; i++)
        #pragma unroll
        for (int j = 0; j < 4; j++) acc[i][j] = {0.f, 0.f, 0.f, 0.f};

    const int srow = lane >> 2, skcol = (lane & 3) * 8;
    unsigned short* lA0 = &As[(wave * 32 +  0) * 32];
    unsigned short* lA1 = &As[(wave * 32 + 16) * 32];
    unsigned short* lB0 = &Bs[(wave * 32 +  0) * 32];
    unsigned short* lB1 = &Bs[(wave * 32 + 16) * 32];
    const unsigned short* gA0 = Az + (size_t)(bm * 128 + wave * 32 + srow) * 512 + skcol;
    const unsigned short* gA1 = gA0 + (size_t)16 * 512;
    const unsigned short* gB0 = Bz + (size_t)(bn * 128 + wave * 32 + srow) * 512 + skcol;
    const unsigned short* gB1 = gB0 + (size_t)16 * 512;

    for (int k0 = 0; k0 < 512; k0 += 32) {
        async_copy16(gA0 + k0, lA0);
        async_copy16(gA1 + k0, lA1);
        async_copy16(gB0 + k0, lB0);
        async_copy16(gB1 + k0, lB1);
        __syncthreads();
        bf16x8 af[4], bfr[4];
        #pragma unroll
        for (int i = 0; i < 4; i++)
            af[i] = *reinterpret_cast<const bf16x8*>(&As[(wm * 64 + i * 16 + l15) * 32 + quad * 8]);
        #pragma unroll
        for (int j = 0; j < 4; j++)
            bfr[j] = *reinterpret_cast<const bf16x8*>(&Bs[(wn * 64 + j * 16 + l15) * 32 + quad * 8]);
        #pragma unroll
        for (int i = 0; i < 4; i++)
            #pragma unroll
            for (int j = 0; j < 4; j++)
                acc[i][j] = __builtin_amdgcn_mfma_f32_16x16x32_bf16(af[i], bfr[j], acc[i][j], 0, 0, 0);
        __syncthreads();
    }

    // Fused epilogue: sim = dot * r_i * r_j / TEMP; rowsumexp, diag, total
    float rc4[4];
    #pragma unroll
    for (int j = 0; j < 4; j++)
        rc4[j] = rnorm[8192 + bn * 128 + wn * 64 + j * 16 + l15];

    float s_total = 0.f, s_diag = 0.f;
    #pragma unroll
    for (int i = 0; i < 4; i++) {
        #pragma unroll
        for (int r = 0; r < 4; r++) {
            const int row_g = bm * 128 + wm * 64 + i * 16 + quad * 4 + r;
            const float rz = rnorm[row_g];
            float rowexp = 0.f;
            #pragma unroll
            for (int j = 0; j < 4; j++) {
                const int col_g = bn * 128 + wn * 64 + j * 16 + l15;
                const float sim = acc[i][j][r] * rz * rc4[j] * 10.0f;  // 1/TEMP
                s_total += sim;
                rowexp += __expf(sim);
                if (col_g == row_g) s_diag += sim;
            }
            rowexp += __shfl_xor(rowexp, 1, 16);
            rowexp += __shfl_xor(rowexp, 2, 16);
            rowexp += __shfl_xor(rowexp, 4, 16);
            rowexp += __shfl_xor(rowexp, 8, 16);
            if (l15 == 0) atomicAdd(&rowse[row_g], rowexp);
        }
    }
    #pragma unroll
    for (int off = 32; off; off >>= 1) {
        s_total += __shfl_xor(s_total, off, 64);
        s_diag  += __shfl_xor(s_diag, off, 64);
    }
    if (lane == 0) { red[wave] = s_total; red[4 + wave] = s_diag; }
    __syncthreads();
    if (t == 0) {
        bsum[bm * 64 + bn]  = red[0] + red[1] + red[2] + red[3];
        bdiag[bm * 64 + bn] = red[4] + red[5] + red[6] + red[7];
    }
}

// ---------------------------------------------------------------- finalize
__global__ __launch_bounds__(256) void finalize_kernel(
    const float* __restrict__ rowse, const float* __restrict__ bsum,
    const float* __restrict__ bdiag, float* __restrict__ out)
{
    float a = 0.f, b = 0.f, c = 0.f;
    for (int i = threadIdx.x; i < 8192; i += 256) a += logf(rowse[i]);
    for (int i = threadIdx.x; i < 4096; i += 256) { b += bsum[i]; c += bdiag[i]; }
    #pragma unroll
    for (int off = 32; off; off >>= 1) {
        a += __shfl_xor(a, off, 64);
        b += __shfl_xor(b, off, 64);
        c += __shfl_xor(c, off, 64);
    }
    __shared__ float ra[4], rb[4], rc[4];
    const int wave = threadIdx.x >> 6, lane = threadIdx.x & 63;
    if (lane == 0) { ra[wave] = a; rb[wave] = b; rc[wave] = c; }
    __syncthreads();
    if (threadIdx.x == 0) {
        const float A = ra[0] + ra[1] + ra[2] + ra[3];
        const float B = rb[0] + rb[1] + rb[2] + rb[3];
        const float C = rc[0] + rc[1] + rc[2] + rc[3];
        const float diag_mean = C / 8192.f;
        out[0] = A / 8192.f - diag_mean;            // loss
        out[1] = diag_mean;                         // sim_pos
        out[2] = B / (8192.f * 8192.f);             // sim_mean
    }
}

// ---------------------------------------------------------------- launch
extern "C" void kernel_launch(void* const* d_in, const int* in_sizes, int n_in,
                              void* d_out, int out_size, void* d_ws, size_t ws_size,
                              hipStream_t stream) {
    const float* h = (const float*)d_in[0];   // [16384, 2048]
    const float* W = (const float*)d_in[1];   // [512, 2048]
    float* out = (float*)d_out;               // [3]

    char* ws = (char*)d_ws;
    float* norm2 = (float*)(ws);                           // 16384 f
    float* rowse = (float*)(ws + 65536);                   // 8192 f
    float* bsum  = (float*)(ws + 98304);                   // 4096 f
    float* bdiag = (float*)(ws + 114688);                  // 4096 f
    float* rnorm = (float*)(ws + 131072);                  // 16384 f
    unsigned short* Zb = (unsigned short*)(ws + 196608);   // 16384x512 bf16 (16.78 MB)
    unsigned short* Wb = (unsigned short*)(ws + 16973824); // 512x2048 bf16 (2 MB)
    unsigned short* hb = (unsigned short*)(ws + 19070976); // 16384x2048 bf16 (67.1 MB)
    const size_t NEED_FAST = 19070976ull + 67108864ull;    // ~86.2 MB

    hipMemsetAsync(ws, 0, 131072, stream);    // zero atomic accumulators

    if (ws_size >= NEED_FAST) {
        const int nh = 16384 * 2048, nw = 512 * 2048;
        hipLaunchKernelGGL(cast_kernel, dim3(nh / 2048), dim3(256), 0, stream, h, hb, nh);
        hipLaunchKernelGGL(cast_kernel, dim3(nw / 2048), dim3(256), 0, stream, W, Wb, nw);
        hipLaunchKernelGGL(gemm1_fast_kernel, dim3(4, 128), dim3(256), 0, stream, hb, Wb, Zb, norm2);
    } else {
        hipLaunchKernelGGL(gemm1_slow_kernel, dim3(4, 128), dim3(256), 0, stream, h, W, Zb, norm2);
    }
    hipLaunchKernelGGL(rnorm_kernel, dim3(64), dim3(256), 0, stream, norm2, rnorm);
    hipLaunchKernelGGL(gemm2_kernel, dim3(64, 64), dim3(256), 0, stream, Zb, rnorm, rowse, bsum, bdiag);
    hipLaunchKernelGGL(finalize_kernel, dim3(1), dim3(256), 0, stream, rowse, bsum, bdiag, out);
}